// Round 4
// baseline (463.567 us; speedup 1.0000x reference)
//
#include <hip/hip_runtime.h>

#define NN 1024
#define FF 64
#define NBT 64
#define INV_LN2 1.44269504088896f

typedef float f32x4 __attribute__((ext_vector_type(4)));
typedef short s16x8 __attribute__((ext_vector_type(8)));

__device__ __forceinline__ short f2bf(float f) {
    unsigned u = __builtin_bit_cast(unsigned, f);
    u = (u + 0x7FFFu + ((u >> 16) & 1u)) >> 16;
    return (short)u;
}

// Kernel 1: Wh = h @ W (fp32 compute). Outputs:
//   WhT  bf16  [bt][c][j]   (transposed so k2 B-fragments are contiguous in j)
//   s1,s2 fp32 [bt][j]      (Wh.a1, Wh.a2) PRE-SCALED by 1/ln2 (log2 domain).
__global__ __launch_bounds__(256) void k1(const float* __restrict__ h,
                                          const float* __restrict__ W,
                                          const float* __restrict__ a,
                                          short* __restrict__ WhT,
                                          float* __restrict__ s1g,
                                          float* __restrict__ s2g) {
    __shared__ float Wl[64 * 64];   // [k][c]
    __shared__ float al[128];
    __shared__ float s1sh[128], s2sh[128];
    const int blk = blockIdx.x;
    const int bt = blk >> 3;
    const int rbase = (blk & 7) * 128;
    const int t = threadIdx.x;

    for (int i = t; i < 1024; i += 256)
        ((f32x4*)Wl)[i] = ((const f32x4*)W)[i];
    if (t < 32) ((f32x4*)al)[t] = ((const f32x4*)a)[t];
    __syncthreads();

    const int row = rbase + (t & 127);
    const int half = t >> 7;           // 0: c 0..31, 1: c 32..63
    const float* hrow = h + ((size_t)bt * NN + row) * FF;
    float hv[64];
#pragma unroll
    for (int i = 0; i < 16; i++)
        ((f32x4*)hv)[i] = ((const f32x4*)hrow)[i];

    float s1 = 0.f, s2 = 0.f;
    short* wt = WhT + (size_t)bt * FF * NN + row;
#pragma unroll
    for (int cgi = 0; cgi < 8; cgi++) {
        const int cg = half * 8 + cgi;       // float4 group of columns
        f32x4 acc = {0.f, 0.f, 0.f, 0.f};
#pragma unroll
        for (int k = 0; k < 64; k++) {
            f32x4 w4 = ((const f32x4*)Wl)[k * 16 + cg];  // broadcast read
            acc += hv[k] * w4;
        }
        const int c0 = cg * 4;
        s1 += acc.x * al[c0] + acc.y * al[c0 + 1] + acc.z * al[c0 + 2] + acc.w * al[c0 + 3];
        s2 += acc.x * al[64 + c0] + acc.y * al[64 + c0 + 1] + acc.z * al[64 + c0 + 2] + acc.w * al[64 + c0 + 3];
        wt[(size_t)(c0 + 0) * NN] = f2bf(acc.x);
        wt[(size_t)(c0 + 1) * NN] = f2bf(acc.y);
        wt[(size_t)(c0 + 2) * NN] = f2bf(acc.z);
        wt[(size_t)(c0 + 3) * NN] = f2bf(acc.w);
    }
    if (half == 1) { s1sh[t & 127] = s1; s2sh[t & 127] = s2; }
    __syncthreads();
    if (half == 0) {
        s1g[bt * NN + row] = (s1 + s1sh[t]) * INV_LN2;
        s2g[bt * NN + row] = (s2 + s2sh[t]) * INV_LN2;
    }
}

// Kernel 2: masked-softmax attention + P @ Wh via bf16 MFMA, + elu.
// grid 1024 = 64 batches x 16 row-tiles (64 rows). 256 threads = 4 waves,
// wave wv owns rows wv*16..+15 (its own MFMA A rows).
//
// KEY CHANGE vs rounds 0-3: adj is never read in MFMA-tile order (16 rows x
// 128B at 4KB stride = 16 lines on one HBM channel per instruction -- that
// pattern capped adj bandwidth at ~1.9 TB/s in every prior round). Instead
// each wave streams its 16 rows ROW-SEQUENTIALLY (256B contiguous per
// instruction), packs adj>0 into bits via __ballot (64 cols/instr), and
// stores 128B/row into LDS. Inner loop reads 4B of bits per lane from LDS.
//
// Softmax factored out of the inner loop:
//   exp2(leaky(s1+s2)) = max(E1*F1[j], E2*F2[j]),
//   E1=exp2(s1), E2=exp2(0.2*s1) per row; F1/F2 per column, precomputed
//   once per block into LDS (removes exp + add from the hot loop).
// Rowsum via 5th MFMA with B = ones.
__global__ __launch_bounds__(256, 4) void k2(const int* __restrict__ adj,
                                             const short* __restrict__ WhT,
                                             const float* __restrict__ s1g,
                                             const float* __restrict__ s2g,
                                             float* __restrict__ out) {
    __shared__ float F1[NN], F2[NN];
    __shared__ __align__(8) unsigned adjb[64 * 34];  // [row][34 words]; stride 34
                                                     // = 8B-aligned rows + 2-way-max banks

    const int bx = blockIdx.x;
    const int bt = bx >> 4;
    const int ibase = (bx & 15) * 64;
    const int t = threadIdx.x;
    const int wv = t >> 6;
    const int l = t & 63;
    const int m = l & 15;      // A row within wave tile / B column
    const int q = l >> 4;      // k-group (j octet)

    // --- per-column factors F1/F2 (shared by all 4 waves) ---
    for (int i = t; i < NN; i += 256) {
        float s2v = s2g[bt * NN + i];                // log2-domain
        F1[i] = fminf(exp2f(s2v), 1e9f);             // clamp ~2^30: product stays finite
        F2[i] = fminf(exp2f(0.2f * s2v), 1e9f);
    }

    // --- adj staging: wave-private rows, row-sequential reads, ballot-packed ---
    {
        const int* ap = adj + ((size_t)bt * NN + ibase + wv * 16) * NN + l;
        for (int g = 0; g < 16; g++) {               // 64-column groups
            int v[16];
#pragma unroll
            for (int r = 0; r < 16; r++)             // 16 rows: 256B contiguous each
                v[r] = ap[(size_t)r * NN + g * 64];
            unsigned long long keep = 0;
#pragma unroll
            for (int r = 0; r < 16; r++) {
                unsigned long long bal = __ballot(v[r] != 0);  // bit l = col g*64+l
                if (l == r) keep = bal;              // lane r captures row r's bits
            }
            if (l < 16)
                *(unsigned long long*)&adjb[(wv * 16 + l) * 34 + g * 2] = keep;
        }
    }

    const int row = ibase + wv * 16 + m;
    const float s1v = s1g[bt * NN + row];            // log2-domain
    const float E1 = fminf(exp2f(s1v), 1e9f);
    const float E2 = fminf(exp2f(0.2f * s1v), 1e9f);

    const short* whp = WhT + (size_t)bt * FF * NN + (size_t)m * NN + q * 8;
    const unsigned* myrow = &adjb[(wv * 16 + m) * 34];

    f32x4 acc0 = {0.f, 0.f, 0.f, 0.f};
    f32x4 acc1 = {0.f, 0.f, 0.f, 0.f};
    f32x4 acc2 = {0.f, 0.f, 0.f, 0.f};
    f32x4 acc3 = {0.f, 0.f, 0.f, 0.f};
    f32x4 accR = {0.f, 0.f, 0.f, 0.f};
    const s16x8 ones = {0x3F80, 0x3F80, 0x3F80, 0x3F80, 0x3F80, 0x3F80, 0x3F80, 0x3F80};

    // prefetch B-fragments for tile 0 (WhT is L2-resident: 128KB/bt, 16 blocks share)
    s16x8 cb0 = *(const s16x8*)(whp);
    s16x8 cb1 = *(const s16x8*)(whp + 16 * NN);
    s16x8 cb2 = *(const s16x8*)(whp + 32 * NN);
    s16x8 cb3 = *(const s16x8*)(whp + 48 * NN);

    __syncthreads();   // F1/F2 ready (adjb is wave-private: no barrier needed for it)

    for (int jt = 0; jt < 32; jt++) {
        const int jn = (jt < 31 ? jt + 1 : 31) * 32;   // dup last: harmless
        s16x8 nb0 = *(const s16x8*)(whp + jn);
        s16x8 nb1 = *(const s16x8*)(whp + 16 * NN + jn);
        s16x8 nb2 = *(const s16x8*)(whp + 32 * NN + jn);
        s16x8 nb3 = *(const s16x8*)(whp + 48 * NN + jn);

        const unsigned word = myrow[jt];               // LDS: this row's 32 mask bits
        const unsigned mb = (word >> (q * 8)) & 255u;  // this lane's 8 bits

        f32x4 f1a = *(const f32x4*)&F1[jt * 32 + q * 8];
        f32x4 f1b = *(const f32x4*)&F1[jt * 32 + q * 8 + 4];
        f32x4 f2a = *(const f32x4*)&F2[jt * 32 + q * 8];
        f32x4 f2b = *(const f32x4*)&F2[jt * 32 + q * 8 + 4];
        const float v1[8] = {f1a.x, f1a.y, f1a.z, f1a.w, f1b.x, f1b.y, f1b.z, f1b.w};
        const float v2[8] = {f2a.x, f2a.y, f2a.z, f2a.w, f2b.x, f2b.y, f2b.z, f2b.w};

        s16x8 af;
#pragma unroll
        for (int u = 0; u < 8; u++) {
            float pe = fmaxf(E1 * v1[u], E2 * v2[u]);  // exp2(leaky(s1+s2))
            float p = (mb & (1u << u)) ? pe : 0.f;
            af[u] = f2bf(p);
        }

        acc0 = __builtin_amdgcn_mfma_f32_16x16x32_bf16(af, cb0, acc0, 0, 0, 0);
        acc1 = __builtin_amdgcn_mfma_f32_16x16x32_bf16(af, cb1, acc1, 0, 0, 0);
        acc2 = __builtin_amdgcn_mfma_f32_16x16x32_bf16(af, cb2, acc2, 0, 0, 0);
        acc3 = __builtin_amdgcn_mfma_f32_16x16x32_bf16(af, cb3, acc3, 0, 0, 0);
        accR = __builtin_amdgcn_mfma_f32_16x16x32_bf16(af, ones, accR, 0, 0, 0);

        cb0 = nb0; cb1 = nb1; cb2 = nb2; cb3 = nb3;
    }

    float rinv[4];
#pragma unroll
    for (int e = 0; e < 4; e++)
        rinv[e] = accR[e] > 0.f ? 1.f / accR[e] : 0.f;

    float* outp = out + ((size_t)bt * NN + ibase + wv * 16 + q * 4) * FF + m;
#pragma unroll
    for (int e = 0; e < 4; e++) {
        float v0 = acc0[e] * rinv[e];
        float v1o = acc1[e] * rinv[e];
        float v2o = acc2[e] * rinv[e];
        float v3o = acc3[e] * rinv[e];
        v0  = v0  > 0.f ? v0  : expm1f(v0);
        v1o = v1o > 0.f ? v1o : expm1f(v1o);
        v2o = v2o > 0.f ? v2o : expm1f(v2o);
        v3o = v3o > 0.f ? v3o : expm1f(v3o);
        float* o = outp + (size_t)e * FF;
        o[0]  = v0;
        o[16] = v1o;
        o[32] = v2o;
        o[48] = v3o;
    }
}

extern "C" void kernel_launch(void* const* d_in, const int* in_sizes, int n_in,
                              void* d_out, int out_size, void* d_ws, size_t ws_size,
                              hipStream_t stream) {
    const float* h  = (const float*)d_in[0];
    const int*  adj = (const int*)d_in[1];
    const float* W  = (const float*)d_in[2];
    const float* a  = (const float*)d_in[3];
    float* out = (float*)d_out;

    short* WhT = (short*)d_ws;                                      // 64*64*1024*2 = 8 MB
    float* s1  = (float*)((char*)d_ws + (size_t)NBT * FF * NN * 2); // 256 KB
    float* s2  = s1 + NBT * NN;                                     // 256 KB

    k1<<<512, 256, 0, stream>>>(h, W, a, WhT, s1, s2);
    k2<<<1024, 256, 0, stream>>>(adj, WhT, s1, s2, out);
}

// Round 5
// 415.525 us; speedup vs baseline: 1.1156x; 1.1156x over previous
//
#include <hip/hip_runtime.h>

#define NN 1024
#define FF 64
#define NBT 64
#define INV_LN2 1.44269504088896f

typedef float f32x4 __attribute__((ext_vector_type(4)));
typedef short s16x8 __attribute__((ext_vector_type(8)));

__device__ __forceinline__ short f2bf(float f) {
    unsigned u = __builtin_bit_cast(unsigned, f);
    u = (u + 0x7FFFu + ((u >> 16) & 1u)) >> 16;
    return (short)u;
}

// Kernel 1: Wh = h @ W (fp32 compute). Outputs:
//   WhT  bf16  [bt][c][j]   (transposed so k2 B-fragments are contiguous in j)
//   s1,s2 fp32 [bt][j]      (Wh.a1, Wh.a2) PRE-SCALED by 1/ln2 (log2 domain:
//   leaky_relu commutes with positive scaling, so k2 uses raw v_exp_f32).
__global__ __launch_bounds__(256) void k1(const float* __restrict__ h,
                                          const float* __restrict__ W,
                                          const float* __restrict__ a,
                                          short* __restrict__ WhT,
                                          float* __restrict__ s1g,
                                          float* __restrict__ s2g) {
    __shared__ float Wl[64 * 64];   // [k][c]
    __shared__ float al[128];
    __shared__ float s1sh[128], s2sh[128];
    const int blk = blockIdx.x;
    const int bt = blk >> 3;
    const int rbase = (blk & 7) * 128;
    const int t = threadIdx.x;

    for (int i = t; i < 1024; i += 256)
        ((f32x4*)Wl)[i] = ((const f32x4*)W)[i];
    if (t < 32) ((f32x4*)al)[t] = ((const f32x4*)a)[t];
    __syncthreads();

    const int row = rbase + (t & 127);
    const int half = t >> 7;           // 0: c 0..31, 1: c 32..63
    const float* hrow = h + ((size_t)bt * NN + row) * FF;
    float hv[64];
#pragma unroll
    for (int i = 0; i < 16; i++)
        ((f32x4*)hv)[i] = ((const f32x4*)hrow)[i];

    float s1 = 0.f, s2 = 0.f;
    short* wt = WhT + (size_t)bt * FF * NN + row;
#pragma unroll
    for (int cgi = 0; cgi < 8; cgi++) {
        const int cg = half * 8 + cgi;       // float4 group of columns
        f32x4 acc = {0.f, 0.f, 0.f, 0.f};
#pragma unroll
        for (int k = 0; k < 64; k++) {
            f32x4 w4 = ((const f32x4*)Wl)[k * 16 + cg];  // broadcast read
            acc += hv[k] * w4;
        }
        const int c0 = cg * 4;
        s1 += acc.x * al[c0] + acc.y * al[c0 + 1] + acc.z * al[c0 + 2] + acc.w * al[c0 + 3];
        s2 += acc.x * al[64 + c0] + acc.y * al[64 + c0 + 1] + acc.z * al[64 + c0 + 2] + acc.w * al[64 + c0 + 3];
        wt[(size_t)(c0 + 0) * NN] = f2bf(acc.x);
        wt[(size_t)(c0 + 1) * NN] = f2bf(acc.y);
        wt[(size_t)(c0 + 2) * NN] = f2bf(acc.z);
        wt[(size_t)(c0 + 3) * NN] = f2bf(acc.w);
    }
    if (half == 1) { s1sh[t & 127] = s1; s2sh[t & 127] = s2; }
    __syncthreads();
    if (half == 0) {
        s1g[bt * NN + row] = (s1 + s1sh[t]) * INV_LN2;
        s2g[bt * NN + row] = (s2 + s2sh[t]) * INV_LN2;
    }
}

// Kernel 2: masked-softmax attention + P @ Wh via bf16 MFMA, + elu.
// == ROUND-0 STRUCTURE RESTORED (best timed total: 415.7) ==
// grid 1024 = 64 batches x 16 row-tiles (64 rows). 256 threads = 4 waves.
// Staging role: thread t -> row r=t>>2 (of 64), j-chunk jc=(t&3)*8.
// MFMA role: wave wv owns rows wv*16..+15; 4 c-groups of 16.
// Surgical deltas vs round 0 (each small, mechanism-understood):
//  (a) ping-pong Pa/Pw buffers -> ONE barrier per tile instead of two;
//  (b) prefetch for tile jt+1 issued AFTER the barrier (round 0 issued it
//      before, so the barrier's implicit vmcnt(0) drain discarded the
//      overlap; now the loads stay in flight under ds_read+MFMA);
//  (c) exp2-domain softmax (s1/s2 pre-scaled; validated r2-r4);
//  (d) rowsum via 5th MFMA with B=ones (removes 8 VALU adds/tile/thread
//      and the shuffle epilogue; MFMA pipe is 2% busy);
//  (e) XCD swizzle: the 16 blocks sharing WhT[bt] land on one XCD's L2.
__global__ __launch_bounds__(256) void k2(const int* __restrict__ adj,
                                          const short* __restrict__ WhT,
                                          const float* __restrict__ s1g,
                                          const float* __restrict__ s2g,
                                          float* __restrict__ out) {
    __shared__ __align__(16) short Pa[2][64 * 40];   // P tile  [i][j], pad 32->40
    __shared__ __align__(16) short Pw[2][64 * 40];   // Wh tile [c][j], pad 32->40
    __shared__ float s2l[NN];

    const int bxl = blockIdx.x;
    const int bx = (bxl & 7) * 128 + (bxl >> 3);   // bijective XCD swizzle (1024 = 8*128)
    const int bt = bx >> 4;
    const int ibase = (bx & 15) * 64;
    const int t = threadIdx.x;

    // stage the full s2 row for this batch (reused by all 32 j-tiles)
    ((f32x4*)s2l)[t] = ((const f32x4*)(s2g + (size_t)bt * NN))[t];

    const int r = t >> 2;
    const int jc = (t & 3) * 8;
    const float s1v = s1g[bt * NN + ibase + r];    // log2-domain

    const int* adjp = adj + ((size_t)bt * NN + ibase + r) * NN + jc;
    const short* whp = WhT + (size_t)bt * FF * NN + (size_t)r * NN + jc;

    const int wv = t >> 6;
    const int l = t & 63;
    const int m = l & 15;
    const int q = l >> 4;
    const int foff = (wv * 16 + m) * 40 + q * 8;   // A-frag offset within Pa[b]
    const int boff0 = (0 * 16 + m) * 40 + q * 8;   // B-frag offsets within Pw[b]
    const int boff1 = (1 * 16 + m) * 40 + q * 8;
    const int boff2 = (2 * 16 + m) * 40 + q * 8;
    const int boff3 = (3 * 16 + m) * 40 + q * 8;

    f32x4 acc0 = {0.f, 0.f, 0.f, 0.f};
    f32x4 acc1 = {0.f, 0.f, 0.f, 0.f};
    f32x4 acc2 = {0.f, 0.f, 0.f, 0.f};
    f32x4 acc3 = {0.f, 0.f, 0.f, 0.f};
    f32x4 accR = {0.f, 0.f, 0.f, 0.f};
    const s16x8 ones = {0x3F80, 0x3F80, 0x3F80, 0x3F80, 0x3F80, 0x3F80, 0x3F80, 0x3F80};

    // prefetch tile 0
    int4 ca0 = *(const int4*)(adjp);
    int4 ca1 = *(const int4*)(adjp + 4);
    int4 cw  = *(const int4*)(whp);

    __syncthreads();   // s2l ready

    for (int jt = 0; jt < 32; jt++) {
        const int b = jt & 1;

        // compute P = adj ? exp2(leaky(s1+s2)) : 0  (log2 domain, no max-sub)
        int aj[8] = {ca0.x, ca0.y, ca0.z, ca0.w, ca1.x, ca1.y, ca1.z, ca1.w};
        f32x4 s2a = *(const f32x4*)&s2l[jt * 32 + jc];
        f32x4 s2b = *(const f32x4*)&s2l[jt * 32 + jc + 4];
        float sv[8] = {s2a.x, s2a.y, s2a.z, s2a.w, s2b.x, s2b.y, s2b.z, s2b.w};
        s16x8 pbv;
#pragma unroll
        for (int u = 0; u < 8; u++) {
            float e = s1v + sv[u];
            e = fmaxf(e, 0.2f * e);            // leaky_relu (scale-commutes)
            e = fminf(e, 86.f);                // paranoia clamp, never active
            float p = (aj[u] > 0) ? exp2f(e) : 0.f;
            pbv[u] = f2bf(p);
        }
        *(s16x8*)&Pa[b][r * 40 + jc] = pbv;
        *(int4*)&Pw[b][r * 40 + jc] = cw;
        __syncthreads();                       // buf b staged (single drain point)

        // prefetch tile jt+1 NOW -- stays in flight under ds_read + MFMA
        const int jn = (jt < 31 ? jt + 1 : 31) * 32;   // dup last: harmless
        int4 na0 = *(const int4*)(adjp + jn);
        int4 na1 = *(const int4*)(adjp + jn + 4);
        int4 nw  = *(const int4*)(whp + jn);

        s16x8 af = *(const s16x8*)&Pa[b][foff];
        acc0 = __builtin_amdgcn_mfma_f32_16x16x32_bf16(af, *(const s16x8*)&Pw[b][boff0], acc0, 0, 0, 0);
        acc1 = __builtin_amdgcn_mfma_f32_16x16x32_bf16(af, *(const s16x8*)&Pw[b][boff1], acc1, 0, 0, 0);
        acc2 = __builtin_amdgcn_mfma_f32_16x16x32_bf16(af, *(const s16x8*)&Pw[b][boff2], acc2, 0, 0, 0);
        acc3 = __builtin_amdgcn_mfma_f32_16x16x32_bf16(af, *(const s16x8*)&Pw[b][boff3], acc3, 0, 0, 0);
        accR = __builtin_amdgcn_mfma_f32_16x16x32_bf16(af, ones, accR, 0, 0, 0);
        // NOTE: no second barrier -- buf b is only rewritten at jt+2, which is
        // after every thread passes the jt+1 barrier, and a thread reaches that
        // barrier only after its own ds_reads of buf b completed (program order).

        ca0 = na0; ca1 = na1; cw = nw;
    }

    // accR[e] = rowsum(wv*16 + q*4 + e) -- exactly this lane's C rows
    float rinv[4];
#pragma unroll
    for (int e = 0; e < 4; e++)
        rinv[e] = accR[e] > 0.f ? 1.f / accR[e] : 0.f;

    float* outp = out + ((size_t)bt * NN + ibase + wv * 16 + q * 4) * FF + m;
#pragma unroll
    for (int e = 0; e < 4; e++) {
        float v0 = acc0[e] * rinv[e];
        float v1 = acc1[e] * rinv[e];
        float v2 = acc2[e] * rinv[e];
        float v3 = acc3[e] * rinv[e];
        v0 = v0 > 0.f ? v0 : expm1f(v0);
        v1 = v1 > 0.f ? v1 : expm1f(v1);
        v2 = v2 > 0.f ? v2 : expm1f(v2);
        v3 = v3 > 0.f ? v3 : expm1f(v3);
        float* o = outp + (size_t)e * FF;
        o[0]  = v0;
        o[16] = v1;
        o[32] = v2;
        o[48] = v3;
    }
}

extern "C" void kernel_launch(void* const* d_in, const int* in_sizes, int n_in,
                              void* d_out, int out_size, void* d_ws, size_t ws_size,
                              hipStream_t stream) {
    const float* h  = (const float*)d_in[0];
    const int*  adj = (const int*)d_in[1];
    const float* W  = (const float*)d_in[2];
    const float* a  = (const float*)d_in[3];
    float* out = (float*)d_out;

    short* WhT = (short*)d_ws;                                      // 64*64*1024*2 = 8 MB
    float* s1  = (float*)((char*)d_ws + (size_t)NBT * FF * NN * 2); // 256 KB
    float* s2  = s1 + NBT * NN;                                     // 256 KB

    k1<<<512, 256, 0, stream>>>(h, W, a, WhT, s1, s2);
    k2<<<1024, 256, 0, stream>>>(adj, WhT, s1, s2, out);
}